// Round 5
// baseline (233.359 us; speedup 1.0000x reference)
//
#include <hip/hip_runtime.h>

#define B_   512
#define N_   512
#define FIN_ 2
#define F_   128
#define G_   512           // 4*F gates
#define XSTRIDE 1040       // floats per x row in LDS (pad -> disjoint banks)
#define HSTRIDE 160        // halfs per h row (320B stride -> rows on disjoint bank halves)

typedef _Float16 half8  __attribute__((ext_vector_type(8)));
typedef float    float4_ __attribute__((ext_vector_type(4)));
typedef float    float2_ __attribute__((ext_vector_type(2)));

#define LOG2E_  1.44269504f
#define LOG2E2_ 2.88539008f

__device__ __forceinline__ float sigmoid_(float x) {
    // 1/(1+2^(-x*log2e)); saturates correctly at +-inf
    return __builtin_amdgcn_rcpf(1.f + __builtin_amdgcn_exp2f(-LOG2E_ * x));
}

// One LSTM step, two batch rows per block mapped to MFMA A-rows 0 and 4.
// C layout (m89): col=lane&15, row=(lane>>4)*4+reg. Row 0 -> lanes 0-15 reg0
// (batch a), row 4 -> lanes 16-31 reg0 (batch b): gate math on 32 lanes, each
// lane owning 1 dim x 4 gates x 1 row, NO cross-lane redistribution.
__device__ __forceinline__ void lstm_step(
    const _Float16* hsrc,            // per-lane: h_lds[buf] + hrow*HSTRIDE
    _Float16* hdst,                  // per-lane write slot (lanes<32)
    float* outp,                     // per-lane HBM slot (lanes<32)
    const half8 (&wf)[4][4], const float (&w0r)[4], const float (&w1r)[4],
    const float (&br)[4], float4_ (&acc)[4], float2_ xv,
    float& cs, int lane, int grp)
{
    // A-fragments: lane (c15,grp) supplies A[c15][k], k = s2*32+grp*8+e.
    half8 af[4];
#pragma unroll
    for (int s2 = 0; s2 < 4; ++s2)
        af[s2] = *reinterpret_cast<const half8*>(hsrc + s2 * 32 + grp * 8);

    // C-init reg0 = per-row x-projection + bias (fp32 exact); regs 1-3 stale.
#pragma unroll
    for (int t = 0; t < 4; ++t)
        acc[t][0] = fmaf(xv[0], w0r[t], fmaf(xv[1], w1r[t], br[t]));

    // h @ Wh : 4 gate-tiles x 4 K-slices (K=128)
#pragma unroll
    for (int s2 = 0; s2 < 4; ++s2)
#pragma unroll
        for (int t = 0; t < 4; ++t)
            acc[t] = __builtin_amdgcn_mfma_f32_16x16x32_f16(af[s2], wf[t][s2], acc[t], 0, 0, 0);

    if (lane < 32) {
        const float gi = sigmoid_(acc[0][0]);
        const float gf = sigmoid_(acc[1][0]);
        // tanh(g) = 1 - 2/(1+2^(g*2log2e))
        const float rg = __builtin_amdgcn_rcpf(1.f + __builtin_amdgcn_exp2f(LOG2E2_ * acc[2][0]));
        const float gg = fmaf(-2.f, rg, 1.f);
        const float go = sigmoid_(acc[3][0]);
        cs = fmaf(gf, cs, gi * gg);
        // h = go * tanh(cs) = fma(-2*go, rc, go): go products hide under rcp latency
        const float rc = __builtin_amdgcn_rcpf(1.f + __builtin_amdgcn_exp2f(LOG2E2_ * cs));
        const float m2go = -2.f * go;
        const float h = fmaf(m2go, rc, go);
        *outp = h;                    // fire-and-forget; NOTHING ever waits vmcnt
        *hdst = (_Float16)h;
    }
    // LDS-visibility-only barrier: never drain vmcnt in the loop.
    asm volatile("s_waitcnt lgkmcnt(0)\n\ts_barrier" ::: "memory");
}

__global__ void __launch_bounds__(512)
lstm_scan(const float* __restrict__ inp, const float* __restrict__ Wk,
          const float* __restrict__ bias, float* __restrict__ out)
{
    const int bb   = blockIdx.x;       // batch rows 2bb, 2bb+1
    const int tid  = threadIdx.x;
    const int w    = tid >> 6;         // wave 0..7, dims [w*16, w*16+16)
    const int lane = tid & 63;
    const int c15  = lane & 15;
    const int grp  = lane >> 4;        // k-group (8 consecutive k)

    __shared__ __align__(64) _Float16 h_lds[2][2 * HSTRIDE];  // ping-pong h
    __shared__ __align__(64) float    x_lds[2 * XSTRIDE];     // staged inputs

    // ---- one-time: weight fragments into registers (64 VGPRs) ----
    // tile t = gate t, col = t*128 + w*16 + c15
    half8 wf[4][4];
    float w0r[4], w1r[4], br[4];
#pragma unroll
    for (int t = 0; t < 4; ++t) {
        const int col = t * F_ + w * 16 + c15;
        w0r[t] = Wk[col];
        w1r[t] = Wk[G_ + col];
        br[t]  = bias[col];
#pragma unroll
        for (int s2 = 0; s2 < 4; ++s2) {
            half8 f;
#pragma unroll
            for (int e = 0; e < 8; ++e)
                f[e] = (_Float16)Wk[(size_t)(2 + s2 * 32 + grp * 8 + e) * G_ + col];
            wf[t][s2] = f;
        }
    }

    // ---- stage x (2 rows x 1024 floats) into padded LDS ----
    {
        const float* xsrc = inp + (size_t)(2 * bb) * (N_ * FIN_);
        const int i4 = tid * 4;                      // 0..2044
        float4_ v = *reinterpret_cast<const float4_*>(xsrc + i4);
        const int row = i4 >> 10, idx = i4 & 1023;
        *reinterpret_cast<float4_*>(&x_lds[row * XSTRIDE + idx]) = v;
    }
    for (int i = tid; i < 2 * 2 * HSTRIDE; i += 512)
        ((_Float16*)h_lds)[i] = (_Float16)0.f;
    __syncthreads();

    const int r    = (lane >> 4) & 1;   // batch sub-row this lane handles
    const int hrow = (c15 >> 2) & 1;    // h-row feeding this lane's A slot

    const _Float16* hr0 = &h_lds[0][hrow * HSTRIDE];
    const _Float16* hr1 = &h_lds[1][hrow * HSTRIDE];
    _Float16* hw0 = &h_lds[0][r * HSTRIDE + w * 16 + c15];
    _Float16* hw1 = &h_lds[1][r * HSTRIDE + w * 16 + c15];
    const float* xq = &x_lds[r * XSTRIDE];   // x for step s lives at xq[2(s-1)]
    float* outp = out + (size_t)(2 * bb + r) * N_ * F_ + w * 16 + c15;

    float cs = 0.f;
    float4_ acc[4];
#pragma unroll
    for (int t = 0; t < 4; ++t) { acc[t][0] = 0.f; acc[t][1] = 0.f; acc[t][2] = 0.f; acc[t][3] = 0.f; }

    float2_ xz; xz[0] = 0.f; xz[1] = 0.f;

    // step 0: x_shift = 0, reads zeroed buf0, writes buf1
    lstm_step(hr0, hw1, outp, wf, w0r, w1r, br, acc, xz, cs, lane, grp);
    outp += F_;

    // steps 1..510 in pairs (odd reads buf1, even reads buf0)
    for (int i = 0; i < 255; ++i) {
        const int s = 2 * i + 1;
        const float2_ xa = *reinterpret_cast<const float2_*>(xq + 2 * (s - 1));
        const float2_ xb = *reinterpret_cast<const float2_*>(xq + 2 * s);
        lstm_step(hr1, hw0, outp, wf, w0r, w1r, br, acc, xa, cs, lane, grp);
        outp += F_;
        lstm_step(hr0, hw1, outp, wf, w0r, w1r, br, acc, xb, cs, lane, grp);
        outp += F_;
    }
    // step 511 (odd): reads buf1
    {
        const float2_ xa = *reinterpret_cast<const float2_*>(xq + 2 * 510);
        lstm_step(hr1, hw0, outp, wf, w0r, w1r, br, acc, xa, cs, lane, grp);
    }
}

extern "C" void kernel_launch(void* const* d_in, const int* in_sizes, int n_in,
                              void* d_out, int out_size, void* d_ws, size_t ws_size,
                              hipStream_t stream) {
    const float* inp  = (const float*)d_in[0];
    const float* Wk   = (const float*)d_in[1];
    const float* bias = (const float*)d_in[2];
    float* out        = (float*)d_out;
    lstm_scan<<<dim3(B_ / 2), dim3(512), 0, stream>>>(inp, Wk, bias, out);
}

// Round 6
// 231.734 us; speedup vs baseline: 1.0070x; 1.0070x over previous
//
#include <hip/hip_runtime.h>

#define B_   512
#define N_   512
#define FIN_ 2
#define F_   128
#define G_   512           // 4*F gates
#define XSTRIDE 1040       // floats per x row in LDS (pad -> disjoint banks)
#define HSTRIDE 160        // halfs per h row (320B stride -> rows on disjoint bank halves)

typedef _Float16 half8  __attribute__((ext_vector_type(8)));
typedef float    float4_ __attribute__((ext_vector_type(4)));
typedef float    float2_ __attribute__((ext_vector_type(2)));

#define LOG2E_  1.44269504f
#define LOG2E2_ 2.88539008f

__device__ __forceinline__ float sigmoid_(float x) {
    // 1/(1+2^(-x*log2e)); saturates correctly at +-inf
    return __builtin_amdgcn_rcpf(1.f + __builtin_amdgcn_exp2f(-LOG2E_ * x));
}

// One LSTM step, two batch rows per block mapped to MFMA A-rows 0 and 4.
// C layout (m89): col=lane&15, row=(lane>>4)*4+reg. A-row hrow(c15) pattern
// repeats with period 8, so C rows 8,12 (lanes 32-63 reg0) are exact DUPS of
// rows 0,4 -> gate math runs branchless on all 64 lanes; dup stores write the
// same values to the same addresses (benign). No exec-mask churn.
__device__ __forceinline__ void lstm_step(
    const _Float16* hsrc,            // per-lane: h_lds[buf] + hrow*HSTRIDE
    _Float16* hdst,                  // per-lane write slot
    float* outp,                     // per-lane HBM slot
    const half8 (&wf)[4][4], const float (&w0r)[4], const float (&w1r)[4],
    const float (&br)[4], float4_ (&acc)[4], float2_ xv,
    float& cs, int grp)
{
    // A-fragments first (longest latency); C-init VALU dual-issues under them.
    half8 af[4];
#pragma unroll
    for (int s2 = 0; s2 < 4; ++s2)
        af[s2] = *reinterpret_cast<const half8*>(hsrc + s2 * 32 + grp * 8);

    // C-init reg0 = per-row x-projection + bias (fp32 exact); regs 1-3 stale.
#pragma unroll
    for (int t = 0; t < 4; ++t)
        acc[t][0] = fmaf(xv[0], w0r[t], fmaf(xv[1], w1r[t], br[t]));

    // h @ Wh : 4 gate-tiles x 4 K-slices (K=128); s2-outer so the final four
    // MFMAs are t0..t3 of s2=3 -> tile-t gate reads can start while later
    // tiles' MFMAs still issue.
#pragma unroll
    for (int s2 = 0; s2 < 4; ++s2)
#pragma unroll
        for (int t = 0; t < 4; ++t)
            acc[t] = __builtin_amdgcn_mfma_f32_16x16x32_f16(af[s2], wf[t][s2], acc[t], 0, 0, 0);

    // Branchless gate math on all 64 lanes (lanes 32-63 compute duplicates).
    const float gi = sigmoid_(acc[0][0]);
    const float gf = sigmoid_(acc[1][0]);
    // tanh(g) = 1 - 2/(1+2^(g*2log2e))
    const float rg = __builtin_amdgcn_rcpf(1.f + __builtin_amdgcn_exp2f(LOG2E2_ * acc[2][0]));
    const float gg = fmaf(-2.f, rg, 1.f);
    const float go = sigmoid_(acc[3][0]);
    cs = fmaf(gf, cs, gi * gg);
    // h = go * tanh(cs) = fma(-2*go, rc, go)
    const float rc = __builtin_amdgcn_rcpf(1.f + __builtin_amdgcn_exp2f(LOG2E2_ * cs));
    const float h = fmaf(-2.f * go, rc, go);
    *hdst = (_Float16)h;              // LDS write first: it gates the barrier
    *outp = h;                        // fire-and-forget; nothing waits vmcnt
    // LDS-visibility-only barrier: never drain vmcnt in the loop.
    asm volatile("s_waitcnt lgkmcnt(0)\n\ts_barrier" ::: "memory");
}

__global__ void __launch_bounds__(512)
lstm_scan(const float* __restrict__ inp, const float* __restrict__ Wk,
          const float* __restrict__ bias, float* __restrict__ out)
{
    const int bb   = blockIdx.x;       // batch rows 2bb, 2bb+1
    const int tid  = threadIdx.x;
    const int w    = tid >> 6;         // wave 0..7, dims [w*16, w*16+16)
    const int lane = tid & 63;
    const int c15  = lane & 15;
    const int grp  = lane >> 4;        // k-group (8 consecutive k)

    __shared__ __align__(64) _Float16 h_lds[2][2 * HSTRIDE];  // ping-pong h
    __shared__ __align__(64) float    x_lds[2 * XSTRIDE];     // staged inputs

    // ---- one-time: weight fragments into registers (64 VGPRs) ----
    // tile t = gate t, col = t*128 + w*16 + c15
    half8 wf[4][4];
    float w0r[4], w1r[4], br[4];
#pragma unroll
    for (int t = 0; t < 4; ++t) {
        const int col = t * F_ + w * 16 + c15;
        w0r[t] = Wk[col];
        w1r[t] = Wk[G_ + col];
        br[t]  = bias[col];
#pragma unroll
        for (int s2 = 0; s2 < 4; ++s2) {
            half8 f;
#pragma unroll
            for (int e = 0; e < 8; ++e)
                f[e] = (_Float16)Wk[(size_t)(2 + s2 * 32 + grp * 8 + e) * G_ + col];
            wf[t][s2] = f;
        }
    }

    // ---- stage x (2 rows x 1024 floats) into padded LDS ----
    {
        const float* xsrc = inp + (size_t)(2 * bb) * (N_ * FIN_);
        const int i4 = tid * 4;                      // 0..2044
        float4_ v = *reinterpret_cast<const float4_*>(xsrc + i4);
        const int row = i4 >> 10, idx = i4 & 1023;
        *reinterpret_cast<float4_*>(&x_lds[row * XSTRIDE + idx]) = v;
    }
    for (int i = tid; i < 2 * 2 * HSTRIDE; i += 512)
        ((_Float16*)h_lds)[i] = (_Float16)0.f;
    __syncthreads();

    const int r    = (lane >> 4) & 1;   // batch sub-row this lane handles
    const int hrow = (c15 >> 2) & 1;    // h-row feeding this lane's A slot

    const _Float16* hr0 = &h_lds[0][hrow * HSTRIDE];
    const _Float16* hr1 = &h_lds[1][hrow * HSTRIDE];
    _Float16* hw0 = &h_lds[0][r * HSTRIDE + w * 16 + c15];
    _Float16* hw1 = &h_lds[1][r * HSTRIDE + w * 16 + c15];
    const float* xq = &x_lds[r * XSTRIDE];   // x for step s lives at xq[2(s-1)]
    float* outp = out + (size_t)(2 * bb + r) * N_ * F_ + w * 16 + c15;

    float cs = 0.f;
    float4_ acc[4];
#pragma unroll
    for (int t = 0; t < 4; ++t) { acc[t][0] = 0.f; acc[t][1] = 0.f; acc[t][2] = 0.f; acc[t][3] = 0.f; }

    float2_ xz; xz[0] = 0.f; xz[1] = 0.f;

    // step 0: x_shift = 0, reads zeroed buf0, writes buf1
    lstm_step(hr0, hw1, outp, wf, w0r, w1r, br, acc, xz, cs, grp);
    outp += F_;

    // x for steps 1,2 — prefetched a full iteration ahead from here on
    float2_ x1 = *reinterpret_cast<const float2_*>(xq + 0);
    float2_ x2 = *reinterpret_cast<const float2_*>(xq + 2);

    // steps 1..510 in pairs (odd reads buf1, even reads buf0)
    for (int i = 0; i < 255; ++i) {
        // prefetch x for steps 2i+3, 2i+4; latency hides under both lstm_steps
        const float2_ xn1 = *reinterpret_cast<const float2_*>(xq + 4 * i + 4);
        const float2_ xn2 = *reinterpret_cast<const float2_*>(xq + 4 * i + 6);
        lstm_step(hr1, hw0, outp, wf, w0r, w1r, br, acc, x1, cs, grp);
        outp += F_;
        lstm_step(hr0, hw1, outp, wf, w0r, w1r, br, acc, x2, cs, grp);
        outp += F_;
        x1 = xn1; x2 = xn2;
    }
    // step 511 (odd): reads buf1; x1 = xq[1020] = x for step 511
    lstm_step(hr1, hw0, outp, wf, w0r, w1r, br, acc, x1, cs, grp);
}

extern "C" void kernel_launch(void* const* d_in, const int* in_sizes, int n_in,
                              void* d_out, int out_size, void* d_ws, size_t ws_size,
                              hipStream_t stream) {
    const float* inp  = (const float*)d_in[0];
    const float* Wk   = (const float*)d_in[1];
    const float* bias = (const float*)d_in[2];
    float* out        = (float*)d_out;
    lstm_scan<<<dim3(B_ / 2), dim3(512), 0, stream>>>(inp, Wk, bias, out);
}